// Round 8
// baseline (67.785 us; speedup 1.0000x reference)
//
#include <hip/hip_runtime.h>

// x [E=512][N=65536] fp32.
//   sum_abs[col] = sum_{e>=1} |x[e][col]|
//   lb = x0 - sum_abs; ub = x0 + sum_abs
//   crossing = lb<=0 && ub>=0 ; dead = ub<=0
//   alpha = crossing ? 1-lb : 1
//   out[0]   = dead?0 : crossing? alpha*x0 - alpha*lb*0.5 : x0
//   out[e>0] = dead?0 : crossing? alpha*x : x
//
// Pipelined single-read: each block owns 32 float4-columns, split into NG=8
// groups of 4. Double-buffered 2x32KiB LDS, staged via global_load_lds
// (width 16). Group g's reduce+scale+store overlaps group g+1's DMA reads,
// so the HBM read and write streams interleave continuously (copy-like mix)
// instead of burst-read / burst-write phase alignment.
// Raw s_barrier + counted vmcnt(2) (never 0 mid-loop); __syncthreads would
// drain vmcnt(0) and serialize the prefetch.

#define EROWS 512
#define CSEG 4                   // float4 columns per group
#define NG 8                     // groups per block
#define BLK 1024
#define NWAVES (BLK / 64)        // 16

__global__ __launch_bounds__(BLK) void ar_pipe(const float* __restrict__ x,
                                               float* __restrict__ out, int n4) {
    __shared__ float4 buf[2][EROWS * CSEG];   // 2 x 32 KiB, [row][cseg] linear
    __shared__ float4 part[NWAVES][CSEG];     // 1 KiB per-wave partials
    __shared__ float4 scale4[CSEG];

    const int t    = threadIdx.x;
    const int cseg = t & (CSEG - 1);          // 0..3
    const int rh   = t >> 2;                  // 0..255 (rows rh and rh+256)
    const int w    = t >> 6;                  // wave id 0..15
    const int lane = t & 63;
    const float4* xv = (const float4*)x;
    float4* ov = (float4*)out;

    const int col4_base = blockIdx.x * (NG * CSEG);

    // Stage one group's 512x4 float4 slab into buf[b] via async DMA.
    // Wave w covers rows [w*32, w*32+32) in 2 issues of 1 KiB.
    // Lane L -> row rowbase+(L>>2), cseg L&3 == LDS base + L*16 (linear).
    auto stage = [&](int g, int b) {
        const int col4_0 = col4_base + g * CSEG;
        #pragma unroll
        for (int i = 0; i < 2; ++i) {
            const int rowbase = w * 32 + i * 16;
            const int row = rowbase + (lane >> 2);
            const float4* gsrc = xv + (size_t)row * n4 + col4_0 + (lane & 3);
            float4* ldst = &buf[b][rowbase * CSEG];   // wave-uniform base
            __builtin_amdgcn_global_load_lds(
                (const __attribute__((address_space(1))) void*)gsrc,
                (__attribute__((address_space(3))) void*)ldst,
                16, 0, 0);
        }
    };

    // prologue: group 0
    stage(0, 0);
    asm volatile("s_waitcnt vmcnt(0)" ::: "memory");
    __builtin_amdgcn_s_barrier();
    asm volatile("" ::: "memory");

    #pragma unroll 1
    for (int g = 0; g < NG; ++g) {
        const int b = g & 1;
        const int col4_0 = col4_base + g * CSEG;

        // issue next group's DMA first (stays in flight across barriers)
        if (g + 1 < NG) stage(g + 1, b ^ 1);

        // read current group's two values (rows rh, rh+256)
        float4 v0 = buf[b][t];            // == [rh][cseg]
        float4 v1 = buf[b][t + 1024];     // == [rh+256][cseg]

        float4 acc;
        acc.x = fabsf(v1.x); acc.y = fabsf(v1.y);
        acc.z = fabsf(v1.z); acc.w = fabsf(v1.w);
        if (t >= CSEG) {                  // t<4 hold row 0 in v0: excluded
            acc.x += fabsf(v0.x); acc.y += fabsf(v0.y);
            acc.z += fabsf(v0.z); acc.w += fabsf(v0.w);
        }
        // wave reduce over lanes sharing a cseg (stride 4)
        #pragma unroll
        for (int d = CSEG; d < 64; d <<= 1) {
            acc.x += __shfl_xor(acc.x, d);
            acc.y += __shfl_xor(acc.y, d);
            acc.z += __shfl_xor(acc.z, d);
            acc.w += __shfl_xor(acc.w, d);
        }
        if (lane < CSEG) part[w][lane] = acc;   // lane l holds cseg l sum

        asm volatile("s_waitcnt lgkmcnt(0)" ::: "memory");
        __builtin_amdgcn_s_barrier();           // B1: part visible
        asm volatile("" ::: "memory");

        if (t < CSEG) {                         // t holds row 0 of cseg t in v0
            float sm[4] = {0.f, 0.f, 0.f, 0.f};
            #pragma unroll
            for (int wv = 0; wv < NWAVES; ++wv) {
                float4 p = part[wv][t];
                sm[0] += p.x; sm[1] += p.y; sm[2] += p.z; sm[3] += p.w;
            }
            float x0[4] = {v0.x, v0.y, v0.z, v0.w};
            float sc[4], o0[4];
            #pragma unroll
            for (int j = 0; j < 4; ++j) {
                float lb = x0[j] - sm[j];
                float ub = x0[j] + sm[j];
                bool crossing = (lb <= 0.f) && (ub >= 0.f);
                bool dead = (ub <= 0.f);
                float alpha = crossing ? (1.f - lb) : 1.f;
                float scl = dead ? 0.f : (crossing ? alpha : 1.f);
                float addv = (crossing && !dead) ? (-alpha * lb * 0.5f) : 0.f;
                sc[j] = scl;
                o0[j] = scl * x0[j] + addv;
            }
            float4 scv = {sc[0], sc[1], sc[2], sc[3]};
            float4 o0v = {o0[0], o0[1], o0[2], o0[3]};
            scale4[t] = scv;
            ov[col4_0 + t] = o0v;               // row 0 output
        }
        asm volatile("s_waitcnt lgkmcnt(0)" ::: "memory");
        __builtin_amdgcn_s_barrier();           // B2: scale4 visible
        asm volatile("" ::: "memory");

        float4 s = scale4[cseg];
        if (t >= CSEG) {                        // row 0 already written
            float4 o;
            o.x = v0.x * s.x; o.y = v0.y * s.y;
            o.z = v0.z * s.z; o.w = v0.w * s.w;
            ov[(size_t)rh * n4 + col4_0 + cseg] = o;
        }
        {
            float4 o;
            o.x = v1.x * s.x; o.y = v1.y * s.y;
            o.z = v1.z * s.z; o.w = v1.w * s.w;
            ov[(size_t)(rh + 256) * n4 + col4_0 + cseg] = o;
        }

        // buffer swap: wait for next group's DMA (allow this iter's 2 stores
        // to stay outstanding -- never drain vmcnt to 0 mid-loop)
        if (g + 1 < NG) {
            asm volatile("s_waitcnt vmcnt(2)" ::: "memory");
        }
        __builtin_amdgcn_s_barrier();           // B3: buf[b^1] ready, buf[b] free
        asm volatile("" ::: "memory");
    }
}

extern "C" void kernel_launch(void* const* d_in, const int* in_sizes, int n_in,
                              void* d_out, int out_size, void* d_ws, size_t ws_size,
                              hipStream_t stream) {
    const float* x = (const float*)d_in[0];
    float* out = (float*)d_out;
    int total = in_sizes[0];     // 512 * 65536
    int N = total / EROWS;       // 65536
    int n4 = N >> 2;             // 16384 float4 per row
    int nblocks = n4 / (NG * CSEG);  // 512

    ar_pipe<<<nblocks, BLK, 0, stream>>>(x, out, n4);
}

// Round 9
// 45.624 us; speedup vs baseline: 1.4857x; 1.4857x over previous
//
#include <hip/hip_runtime.h>

// x [E=512][N=65536] fp32.
//   sum_abs[col] = sum_{e>=1} |x[e][col]|
//   lb = x0 - sum_abs; ub = x0 + sum_abs
//   crossing = lb<=0 && ub>=0 ; dead = ub<=0
//   alpha = crossing ? 1-lb : 1
//   out[0]   = dead?0 : crossing? alpha*x0 - alpha*lb*0.5 : x0
//   out[e>0] = dead?0 : crossing? alpha*x : x
//
// BEST CONFIG (R2, 45.7 us): single global read, 64 KiB LDS slab, BLK=256,
// 2 blocks/CU. Burst-read then burst-write preserves Infinity-Cache
// residency of the input across replays (FETCH ~= input/2). Measured at 93%
// of the D2D copy ceiling for the minimum 268 MB combined traffic.
// Falsified alternatives: higher occupancy (R5: no change), non-temporal
// stores (R7: no change), read/write pipelining (R8: -48%, kills MALL).

#define EROWS 512
#define W4 8                      // float4 column-groups per block (32 cols)
#define BLK 256
#define ROWS_PER_ITER (BLK / W4)  // 32 rows loaded per iteration
#define NITER (EROWS / ROWS_PER_ITER)  // 16

__global__ __launch_bounds__(BLK) void ar_fused(const float* __restrict__ x,
                                                float* __restrict__ out, int n4) {
    __shared__ float4 slab[EROWS * W4];  // 64 KiB: [row][cseg]
    __shared__ float4 part[BLK];         // 4 KiB per-thread partial |x| sums
    __shared__ float4 scale4[W4];

    int t = threadIdx.x;
    int cseg  = t & (W4 - 1);   // 0..7  — this thread's fixed float4 col group
    int rbase = t >> 3;         // 0..31 — starting row
    int col4_0 = blockIdx.x * W4;

    const float4* xv = (const float4*)x;
    float4* ov = (float4*)out;

    // ---- single global read: stage to LDS + accumulate |x| (row 0 excluded)
    float4 acc = {0.f, 0.f, 0.f, 0.f};
    {
        // k = 0 peeled (row 0 exclusion is only possible here, rbase==0)
        float4 v = xv[(size_t)rbase * n4 + col4_0 + cseg];
        slab[rbase * W4 + cseg] = v;
        if (rbase != 0) {
            acc.x += fabsf(v.x); acc.y += fabsf(v.y);
            acc.z += fabsf(v.z); acc.w += fabsf(v.w);
        }
    }
    #pragma unroll
    for (int k = 1; k < NITER; ++k) {
        int row = rbase + k * ROWS_PER_ITER;
        float4 v = xv[(size_t)row * n4 + col4_0 + cseg];
        slab[row * W4 + cseg] = v;
        acc.x += fabsf(v.x); acc.y += fabsf(v.y);
        acc.z += fabsf(v.z); acc.w += fabsf(v.w);
    }
    part[t] = acc;
    __syncthreads();

    // ---- finalize: 8 threads, one per float4 col group
    if (t < W4) {
        float4 s = {0.f, 0.f, 0.f, 0.f};
        for (int j = 0; j < ROWS_PER_ITER; ++j) {
            float4 p = part[j * W4 + t];
            s.x += p.x; s.y += p.y; s.z += p.z; s.w += p.w;
        }
        float4 x0v = slab[t];  // row 0, col group t
        float x0[4] = {x0v.x, x0v.y, x0v.z, x0v.w};
        float sm[4] = {s.x, s.y, s.z, s.w};
        float sc[4], o0[4];
        #pragma unroll
        for (int j = 0; j < 4; ++j) {
            float lb = x0[j] - sm[j];
            float ub = x0[j] + sm[j];
            bool crossing = (lb <= 0.f) && (ub >= 0.f);
            bool dead = (ub <= 0.f);
            float alpha = crossing ? (1.f - lb) : 1.f;
            float scl = dead ? 0.f : (crossing ? alpha : 1.f);
            float addv = (crossing && !dead) ? (-alpha * lb * 0.5f) : 0.f;
            sc[j] = scl;
            o0[j] = scl * x0[j] + addv;
        }
        float4 scv = {sc[0], sc[1], sc[2], sc[3]};
        float4 o0v = {o0[0], o0[1], o0[2], o0[3]};
        scale4[t] = scv;
        ov[col4_0 + t] = o0v;  // row 0 output
    }
    __syncthreads();

    // ---- rescale rows 1..511 from LDS, write out
    for (int i = W4 + t; i < EROWS * W4; i += BLK) {
        int row = i >> 3;       // i / W4
        int cs  = i & (W4 - 1);
        float4 v = slab[i];
        float4 s = scale4[cs];
        float4 o;
        o.x = v.x * s.x; o.y = v.y * s.y;
        o.z = v.z * s.z; o.w = v.w * s.w;
        ov[(size_t)row * n4 + col4_0 + cs] = o;
    }
}

extern "C" void kernel_launch(void* const* d_in, const int* in_sizes, int n_in,
                              void* d_out, int out_size, void* d_ws, size_t ws_size,
                              hipStream_t stream) {
    const float* x = (const float*)d_in[0];
    float* out = (float*)d_out;
    int total = in_sizes[0];     // 512 * 65536
    int N = total / EROWS;       // 65536
    int n4 = N >> 2;             // 16384 float4 per row
    int nblocks = n4 / W4;       // 2048

    ar_fused<<<nblocks, BLK, 0, stream>>>(x, out, n4);
}